// Round 6
// baseline (926.781 us; speedup 1.0000x reference)
//
#include <hip/hip_runtime.h>
#include <hip/hip_bf16.h>
#include <cstdint>
#include <cstddef>

#define S 4096
#define D 2048
#define H 16
#define HD 128
#define F 8192

typedef unsigned short ushort_t;
typedef __attribute__((ext_vector_type(8))) short short8;
typedef __attribute__((ext_vector_type(4))) float floatx4;

__device__ __forceinline__ ushort_t f2bf(float f) {
  union { float f; unsigned u; } v; v.f = f;
  unsigned u = v.u;
  return (ushort_t)((u + 0x7fffu + ((u >> 16) & 1u)) >> 16);
}

__device__ __forceinline__ void async16(void* lds, const void* g) {
  __builtin_amdgcn_global_load_lds(
      (const __attribute__((address_space(1))) unsigned int*)g,
      (__attribute__((address_space(3))) unsigned int*)lds, 16, 0, 0);
}

template <int N>
__device__ __forceinline__ void vmcnt_() {
  static_assert(N >= 0 && N <= 8, "vmcnt range");
  if constexpr (N == 0) asm volatile("s_waitcnt vmcnt(0)" ::: "memory");
  else if constexpr (N == 1) asm volatile("s_waitcnt vmcnt(1)" ::: "memory");
  else if constexpr (N == 2) asm volatile("s_waitcnt vmcnt(2)" ::: "memory");
  else if constexpr (N == 3) asm volatile("s_waitcnt vmcnt(3)" ::: "memory");
  else if constexpr (N == 4) asm volatile("s_waitcnt vmcnt(4)" ::: "memory");
  else if constexpr (N == 5) asm volatile("s_waitcnt vmcnt(5)" ::: "memory");
  else if constexpr (N == 6) asm volatile("s_waitcnt vmcnt(6)" ::: "memory");
  else if constexpr (N == 7) asm volatile("s_waitcnt vmcnt(7)" ::: "memory");
  else asm volatile("s_waitcnt vmcnt(8)" ::: "memory");
}
__device__ __forceinline__ void bar_() { asm volatile("s_barrier" ::: "memory"); }
__device__ __forceinline__ void lgkm0_() {
  asm volatile("s_waitcnt lgkmcnt(0)" ::: "memory");
  __builtin_amdgcn_sched_barrier(0);
}

// ---------------------------------------------------------------- prep kernels

__global__ void cast_bf16(const float* __restrict__ src, ushort_t* __restrict__ dst, int n4) {
  int i = blockIdx.x * blockDim.x + threadIdx.x;
  if (i < n4) {
    float4 v = ((const float4*)src)[i];
    ushort4 o;
    o.x = f2bf(v.x); o.y = f2bf(v.y); o.z = f2bf(v.z); o.w = f2bf(v.w);
    ((ushort4*)dst)[i] = o;
  }
}

__global__ void build_bqkv(const float* __restrict__ bq, const float* __restrict__ bk,
                           const float* __restrict__ bv, float* __restrict__ bqkv) {
  int n = blockIdx.x * blockDim.x + threadIdx.x;
  if (n < 3 * D) {
    float v;
    if (n < D) v = bq[n];
    else if (n < 2 * D) v = bk[n - D];
    else v = bv[n - 2 * D];
    bqkv[n] = v;
  }
}

// dst[c][r] = src[r][c]; fp32 in, bf16 out. block (32,8)
__global__ void transpose_f32_bf16(const float* __restrict__ src, ushort_t* __restrict__ dst,
                                   int ldS, int ldD, long srcBatchStride, long dstBatchRows) {
  __shared__ float t[32][33];
  int b = blockIdx.z;
  src += (size_t)b * srcBatchStride;
  dst += (size_t)b * dstBatchRows * ldD;
  int r0 = blockIdx.x * 32, c0 = blockIdx.y * 32;
  int tx = threadIdx.x, ty = threadIdx.y;
#pragma unroll
  for (int i = 0; i < 4; ++i)
    t[ty + i * 8][tx] = src[(size_t)(r0 + ty + i * 8) * ldS + c0 + tx];
  __syncthreads();
#pragma unroll
  for (int i = 0; i < 4; ++i)
    dst[(size_t)(c0 + ty + i * 8) * ldD + r0 + tx] = f2bf(t[tx][ty + i * 8]);
}

// bf16 transpose with column offset: dst[c][r] = src[r][colOff+c]. block (32,8)
__global__ void transpose_bf16(const ushort_t* __restrict__ src, ushort_t* __restrict__ dst,
                               int ldS, int ldD, int colOff) {
  __shared__ ushort_t t[32][33];
  int r0 = blockIdx.x * 32, c0 = blockIdx.y * 32;
  int tx = threadIdx.x, ty = threadIdx.y;
#pragma unroll
  for (int i = 0; i < 4; ++i)
    t[ty + i * 8][tx] = src[(size_t)(r0 + ty + i * 8) * ldS + colOff + c0 + tx];
  __syncthreads();
#pragma unroll
  for (int i = 0; i < 4; ++i)
    dst[(size_t)(c0 + ty + i * 8) * ldD + r0 + tx] = t[tx][ty + i * 8];
}

// ---------------------------------------------------------------- 4-phase GEMM
// (unchanged from round 4 -- passed, wall win; see round-4 header for ledger)
template <int MODE, int BM>
__global__ __launch_bounds__(512, 2)
void gemm8p(const ushort_t* __restrict__ A, const ushort_t* __restrict__ Bt,
            const float* __restrict__ bias, const float* __restrict__ resid,
            ushort_t* __restrict__ outb, float* __restrict__ outf,
            int M, int N, int K, int gridN) {
  constexpr int MQ = BM / 64;   // m-frags per wave per A-half
  constexpr int LA = BM / 128;  // loads/thread per A half-tile
  __shared__ __align__(16) ushort_t Abuf[2][BM * 64];
  __shared__ __align__(16) ushort_t Bbuf[2][256 * 64];

  const int tid = threadIdx.x;
  const int l = tid & 63, w = tid >> 6;
  const int c16 = l & 15, g = l >> 4;
  const int wm = w >> 2, wn = w & 3;

  // bijective XCD swizzle (m204); consecutive wgid share the A row-panel
  const int nwg = gridDim.x;
  const int q8 = nwg >> 3, r8 = nwg & 7;
  const int xcd = blockIdx.x & 7, bix = blockIdx.x >> 3;
  const int wgid = (xcd < r8 ? xcd * (q8 + 1) : r8 * (q8 + 1) + (xcd - r8) * q8) + bix;
  const int m0 = (wgid / gridN) * BM;
  const int n0 = (wgid % gridN) * 256;

  const size_t Kb = (size_t)K * 2;
  const size_t aHalfB = (size_t)(BM / 2) * Kb;
  const size_t bHalfB = (size_t)128 * Kb;

  const char* aSrc[LA]; char* aLds[LA];
#pragma unroll
  for (int i = 0; i < LA; ++i) {
    int ch = i * 512 + tid;
    int row = ch >> 3;
    aSrc[i] = (const char*)A + (size_t)(m0 + row) * Kb + (((ch ^ row) & 7) << 4);
    aLds[i] = (char*)(&Abuf[0][0]) + ch * 16;
  }
  const char* bSrc[2]; char* bLds[2];
#pragma unroll
  for (int i = 0; i < 2; ++i) {
    int ch = i * 512 + tid;
    int row = ch >> 3;
    bSrc[i] = (const char*)Bt + (size_t)(n0 + row) * Kb + (((ch ^ row) & 7) << 4);
    bLds[i] = (char*)(&Bbuf[0][0]) + ch * 16;
  }

  auto stA = [&](int p, int h, int kByte) {
#pragma unroll
    for (int i = 0; i < LA; ++i)
      async16(aLds[i] + p * (BM * 128) + h * (BM * 64), aSrc[i] + (size_t)h * aHalfB + kByte);
  };
  auto stB = [&](int p, int h, int kByte) {
#pragma unroll
    for (int i = 0; i < 2; ++i)
      async16(bLds[i] + p * 32768 + h * 16384, bSrc[i] + (size_t)h * bHalfB + kByte);
  };

  int rdK[2];
  rdK[0] = ((g ^ (c16 & 7)) << 4);
  rdK[1] = (((4 + g) ^ (c16 & 7)) << 4);
  const char* Ab0 = (const char*)(&Abuf[0][0]);
  const char* Ab1 = Ab0 + BM * 128;
  const char* Bb0 = (const char*)(&Bbuf[0][0]);
  const char* Bb1 = Bb0 + 32768;

  floatx4 acc[2][2][MQ][2];  // [A-half][B-half][mf][nf]
#pragma unroll
  for (int ah = 0; ah < 2; ++ah)
#pragma unroll
    for (int bh = 0; bh < 2; ++bh)
#pragma unroll
      for (int mf = 0; mf < MQ; ++mf)
#pragma unroll
        for (int nf = 0; nf < 2; ++nf) acc[ah][bh][mf][nf] = (floatx4){0.f, 0.f, 0.f, 0.f};

  short8 af[MQ][2], bf0[2][2], bf1[2][2];
  auto ldA = [&](const char* base, int h) {
#pragma unroll
    for (int mf = 0; mf < MQ; ++mf)
#pragma unroll
      for (int kk = 0; kk < 2; ++kk)
        af[mf][kk] = *(const short8*)(base + h * (BM * 64) +
            (wm * (BM / 4) + mf * 16 + c16) * 128 + rdK[kk]);
  };
  auto ldB = [&](const char* base, int h, short8 (&bf)[2][2]) {
#pragma unroll
    for (int nf = 0; nf < 2; ++nf)
#pragma unroll
      for (int kk = 0; kk < 2; ++kk)
        bf[nf][kk] = *(const short8*)(base + h * 16384 +
            (wn * 32 + nf * 16 + c16) * 128 + rdK[kk]);
  };
  auto mma2 = [&](int ah) {
    __builtin_amdgcn_s_setprio(1);
#pragma unroll
    for (int mf = 0; mf < MQ; ++mf)
#pragma unroll
      for (int kk = 0; kk < 2; ++kk) {
#pragma unroll
        for (int nf = 0; nf < 2; ++nf)
          acc[ah][0][mf][nf] = __builtin_amdgcn_mfma_f32_16x16x32_bf16(
              af[mf][kk], bf0[nf][kk], acc[ah][0][mf][nf], 0, 0, 0);
#pragma unroll
        for (int nf = 0; nf < 2; ++nf)
          acc[ah][1][mf][nf] = __builtin_amdgcn_mfma_f32_16x16x32_bf16(
              af[mf][kk], bf1[nf][kk], acc[ah][1][mf][nf], 0, 0, 0);
      }
    __builtin_amdgcn_s_setprio(0);
  };

  // prologue: T0 {A0,B0,B1,A1} + T1 {A0,B0,B1}
  stA(0, 0, 0); stB(0, 0, 0); stB(0, 1, 0); stA(0, 1, 0);
  stA(1, 0, 128); stB(1, 0, 128); stB(1, 1, 128);
  vmcnt_<LA + 4>();
  bar_();

  const int NI = K >> 7;
  for (int i = 0; i < NI; ++i) {
    const bool lastI = (i == NI - 1);
    const int kE = i << 8;

    ldA(Ab0, 0); ldB(Bb0, 0, bf0); ldB(Bb0, 1, bf1);
    stA(1, 1, kE + 128);
    bar_(); lgkm0_();
    mma2(0);
    bar_();

    ldA(Ab0, 1);
    if (!lastI) { stA(0, 0, kE + 256); stB(0, 0, kE + 256); stB(0, 1, kE + 256); }
    bar_(); lgkm0_();
    mma2(1);
    if (lastI) vmcnt_<0>(); else vmcnt_<LA + 4>();
    bar_();

    ldA(Ab1, 0); ldB(Bb1, 0, bf0); ldB(Bb1, 1, bf1);
    if (!lastI) stA(0, 1, kE + 256);
    bar_(); lgkm0_();
    mma2(0);
    bar_();

    ldA(Ab1, 1);
    if (!lastI) { stA(1, 0, kE + 384); stB(1, 0, kE + 384); stB(1, 1, kE + 384); }
    bar_(); lgkm0_();
    mma2(1);
    if (!lastI) { vmcnt_<LA + 4>(); bar_(); }
  }

  // epilogue
#pragma unroll
  for (int ah = 0; ah < 2; ++ah)
#pragma unroll
    for (int bh = 0; bh < 2; ++bh)
#pragma unroll
      for (int nf = 0; nf < 2; ++nf) {
        int gcol = n0 + bh * 128 + wn * 32 + nf * 16 + c16;
        float bj = bias[gcol];
#pragma unroll
        for (int mf = 0; mf < MQ; ++mf) {
          int grow = m0 + ah * (BM / 2) + wm * (BM / 4) + mf * 16 + g * 4;
#pragma unroll
          for (int r = 0; r < 4; ++r) {
            float v = acc[ah][bh][mf][nf][r] + bj;
            size_t o = (size_t)(grow + r) * N + gcol;
            if (MODE == 0) {
              outb[o] = f2bf(v);
            } else if (MODE == 1) {
              outf[o] = v + resid[o];
            } else if (MODE == 2) {
              outb[o] = f2bf(v > 0.f ? v : 0.f);
            } else {
              outf[o] = v;
            }
          }
        }
      }
}

// ---------------------------------------------------------------- flash attention (v4)
// K double-buffered + single-buffer V with ordered counted vmcnt (T3/T4):
// per tile: issue {V(t)->Vs, K(t+1)->Kb[nxt]}; vmcnt(8) [K(t) resident, newer
// 8 in flight]; bar; QK^T(Kb[cur]) + softmax (V(t) lands underneath);
// vmcnt(4) [V(t) resident, K(t+1) flying]; bar; PV(Vs); bar [Vs protected].
// Ledger: Vs overwritten 1 barrier after PV's reads; Kb[p] overwritten >=2
// barriers after its QK^T reads. Never vmcnt(0) except the last tile.
// Softmax P-pack via v_cvt_pk_bf16_f32 (HW RNE == f2bf, 2 ops for 4 elems).
__global__ __launch_bounds__(256, 2)
void attn_kernel(const ushort_t* __restrict__ QKV, const ushort_t* __restrict__ Vt,
                 ushort_t* __restrict__ heads) {
  const int h = blockIdx.y;
  const int tid = threadIdx.x, w = tid >> 6, l = tid & 63;
  const int g = l >> 4, c = l & 15;
  const int q0 = blockIdx.x * 128 + w * 32;
  const float scale = 0.08838834764831845f;  // 1/sqrt(128)

  __shared__ __align__(16) ushort_t Ks[2][64 * 128];  // [buf][t][d] rows 256B, chunk-swizzled
  __shared__ __align__(16) ushort_t Vs[128 * 64];     // [e][t] rows 128B, chunk-swizzled
  __shared__ __align__(16) ushort_t Ps[4][2][16][72]; // wave-private P, pad-72

  short8 qf[2][4];
#pragma unroll
  for (int u = 0; u < 2; ++u)
#pragma unroll
    for (int k0 = 0; k0 < 4; ++k0)
      qf[u][k0] = *(const short8*)(QKV + (size_t)(q0 + u * 16 + c) * (3 * D) + h * HD + k0 * 32 + g * 8);

  floatx4 o[2][8];
#pragma unroll
  for (int u = 0; u < 2; ++u)
#pragma unroll
    for (int j = 0; j < 8; ++j) o[u][j] = (floatx4){0.f, 0.f, 0.f, 0.f};
  float l_run[2] = {0.f, 0.f};

  // prologue: stage K(0) -> Ks[0]
#pragma unroll
  for (int cc = 0; cc < 4; ++cc) {
    int slot = cc * 256 + tid;
    int krow = slot >> 4, kch = slot & 15;
    const char* gk = (const char*)QKV +
        ((size_t)krow * (3 * D) + D + h * HD) * 2 + ((kch ^ (krow & 15)) << 4);
    async16((char*)(&Ks[0][0]) + (size_t)(cc * 256 + w * 64) * 16, gk);
  }

  for (int t0 = 0, ti = 0; t0 < S; t0 += 64, ++ti) {
    const int cur = ti & 1, nxt = cur ^ 1;
    const bool lastT = (t0 + 64 >= S);

    // stage V(t) -> Vs (issued FIRST so vmcnt(4) later isolates it)
#pragma unroll
    for (int cc = 0; cc < 4; ++cc) {
      int slot = cc * 256 + tid;
      int vrow = slot >> 3, vch = slot & 7;
      const char* gv = (const char*)Vt +
          ((size_t)(h * HD + vrow) * S + t0) * 2 + ((vch ^ (vrow & 7)) << 4);
      async16((char*)Vs + (size_t)(cc * 256 + w * 64) * 16, gv);
    }
    // stage K(t+1) -> Ks[nxt]
    if (!lastT) {
#pragma unroll
      for (int cc = 0; cc < 4; ++cc) {
        int slot = cc * 256 + tid;
        int krow = slot >> 4, kch = slot & 15;
        const char* gk = (const char*)QKV +
            ((size_t)(t0 + 64 + krow) * (3 * D) + D + h * HD) * 2 + ((kch ^ (krow & 15)) << 4);
        async16((char*)(&Ks[0][0]) + (size_t)(nxt * 1024 + cc * 256 + w * 64) * 16, gk);
      }
    }
    if (lastT) vmcnt_<4>(); else vmcnt_<8>();  // K(t) resident
    bar_();

    const ushort_t* Kb = &Ks[cur][0];
    floatx4 sc[2][4];
#pragma unroll
    for (int u = 0; u < 2; ++u)
#pragma unroll
      for (int tt = 0; tt < 4; ++tt) sc[u][tt] = (floatx4){0.f, 0.f, 0.f, 0.f};
#pragma unroll
    for (int tt = 0; tt < 4; ++tt) {
      short8 kf[4];
#pragma unroll
      for (int k0 = 0; k0 < 4; ++k0)
        kf[k0] = *(const short8*)(Kb + (tt * 16 + c) * 128 + (((k0 * 4 + g) ^ c) << 3));
#pragma unroll
      for (int u = 0; u < 2; ++u)
#pragma unroll
        for (int k0 = 0; k0 < 4; ++k0)
          sc[u][tt] = __builtin_amdgcn_mfma_f32_16x16x32_bf16(kf[k0], qf[u][k0], sc[u][tt], 0, 0, 0);
    }

#pragma unroll
    for (int u = 0; u < 2; ++u) {
#pragma unroll
      for (int tt = 0; tt < 4; ++tt) {
        float p0 = __expf(sc[u][tt][0] * scale);
        float p1 = __expf(sc[u][tt][1] * scale);
        float p2 = __expf(sc[u][tt][2] * scale);
        float p3 = __expf(sc[u][tt][3] * scale);
        l_run[u] += p0 + p1 + p2 + p3;
        unsigned r0, r1;
        asm("v_cvt_pk_bf16_f32 %0, %1, %2" : "=v"(r0) : "v"(p0), "v"(p1));
        asm("v_cvt_pk_bf16_f32 %0, %1, %2" : "=v"(r1) : "v"(p2), "v"(p3));
        uint2 pk; pk.x = r0; pk.y = r1;
        *reinterpret_cast<uint2*>(&Ps[w][u][c][tt * 16 + g * 4]) = pk;
      }
    }
    __asm__ volatile("s_waitcnt lgkmcnt(0)" ::: "memory");
    if (lastT) vmcnt_<0>(); else vmcnt_<4>();  // V(t) resident, K(t+1) in flight
    bar_();

    short8 pf[2][2];
#pragma unroll
    for (int u = 0; u < 2; ++u)
#pragma unroll
      for (int tk = 0; tk < 2; ++tk)
        pf[u][tk] = *reinterpret_cast<const short8*>(&Ps[w][u][c][tk * 32 + g * 8]);
#pragma unroll
    for (int j = 0; j < 8; ++j) {
#pragma unroll
      for (int tk = 0; tk < 2; ++tk) {
        short8 vf = *(const short8*)(Vs + (j * 16 + c) * 64 + (((tk * 4 + g) ^ (c & 7)) << 3));
#pragma unroll
        for (int u = 0; u < 2; ++u)
          o[u][j] = __builtin_amdgcn_mfma_f32_16x16x32_bf16(pf[u][tk], vf, o[u][j], 0, 0, 0);
      }
    }
    bar_();  // protect Vs (and Ps) before next-iter stores
  }

#pragma unroll
  for (int u = 0; u < 2; ++u) {
    float lt = l_run[u];
    lt += __shfl_xor(lt, 16);
    lt += __shfl_xor(lt, 32);
    float linv[4];
#pragma unroll
    for (int r = 0; r < 4; ++r) linv[r] = 1.f / __shfl(lt, g * 4 + r);
    ushort_t* hp = heads + (size_t)(q0 + u * 16 + g * 4) * D + h * HD + c;
#pragma unroll
    for (int j = 0; j < 8; ++j)
#pragma unroll
      for (int r = 0; r < 4; ++r)
        hp[(size_t)r * D + j * 16] = f2bf(o[u][j][r] * linv[r]);
  }
}

// ---------------------------------------------------------------- LayerNorm
__global__ __launch_bounds__(256)
void ln_kernel(const float* __restrict__ preln, const float* __restrict__ gamma,
               const float* __restrict__ beta, ushort_t* __restrict__ y) {
  int row = blockIdx.x, tid = threadIdx.x;
  const float* p = preln + (size_t)row * D;
  float vals[8];
  float sum = 0.f, ss = 0.f;
#pragma unroll
  for (int k = 0; k < 8; ++k) {
    float v = p[tid + k * 256];
    vals[k] = v; sum += v; ss += v * v;
  }
#pragma unroll
  for (int off = 32; off >= 1; off >>= 1) {
    sum += __shfl_xor(sum, off);
    ss += __shfl_xor(ss, off);
  }
  __shared__ float s1[4], s2[4];
  int w = tid >> 6, l = tid & 63;
  if (l == 0) { s1[w] = sum; s2[w] = ss; }
  __syncthreads();
  sum = s1[0] + s1[1] + s1[2] + s1[3];
  ss = s2[0] + s2[1] + s2[2] + s2[3];
  float mu = sum / (float)D;
  float var = ss / (float)D - mu * mu;
  float rs = rsqrtf(var + 1e-5f);
  ushort_t* yr = y + (size_t)row * D;
#pragma unroll
  for (int k = 0; k < 8; ++k) {
    int d = tid + k * 256;
    yr[d] = f2bf((vals[k] - mu) * rs * gamma[d] + beta[d]);
  }
}

// ---------------------------------------------------------------- launch

extern "C" void kernel_launch(void* const* d_in, const int* in_sizes, int n_in,
                              void* d_out, int out_size, void* d_ws, size_t ws_size,
                              hipStream_t stream) {
  const float* x = (const float*)d_in[0];
  const float* Wq = (const float*)d_in[1];
  const float* bq = (const float*)d_in[2];
  const float* Wk = (const float*)d_in[3];
  const float* bk = (const float*)d_in[4];
  const float* Wv = (const float*)d_in[5];
  const float* bv = (const float*)d_in[6];
  const float* Wp = (const float*)d_in[7];
  const float* bp = (const float*)d_in[8];
  const float* W1 = (const float*)d_in[9];
  const float* b1 = (const float*)d_in[10];
  const float* W2 = (const float*)d_in[11];
  const float* b2 = (const float*)d_in[12];
  const float* gamma = (const float*)d_in[13];
  const float* beta = (const float*)d_in[14];

  char* ws = (char*)d_ws;
  ushort_t* WQKVT = (ushort_t*)(ws + 0);          // 25,165,824  [dead after QKV gemm]
  ushort_t* XB    = (ushort_t*)(ws + 25165824);   // 16,777,216  [dead after QKV gemm]
  float*    BQKV  = (float*)(ws + 41943040);      //     24,576
  ushort_t* WPT   = (ushort_t*)(ws + 41975808);   //  8,388,608
  ushort_t* W1T   = (ushort_t*)(ws + 50364416);   // 33,554,432
  ushort_t* W2T   = (ushort_t*)(ws + 83918848);   // 33,554,432
  ushort_t* QKV   = (ushort_t*)(ws + 117473280);  // 50,331,648  [dead after attn]
  ushort_t* HEADS = (ushort_t*)(ws + 167804928);  // 16,777,216  [dead after proj]
  ushort_t* VT    = (ushort_t*)(ws + 184582144);  // 16,777,216  [dead after attn]
  float*    PRELN = (float*)(ws + 0);             // 33,554,432 over WQKVT+XB
  ushort_t* AB    = (ushort_t*)(ws + 117473280);  // 67,108,864 over QKV+HEADS
  ushort_t* Y     = (ushort_t*)(ws + 184582144);  // 16,777,216 over VT
  float* OUT = (float*)d_out;

  dim3 tb(32, 8);
  cast_bf16<<<(S * D / 4 + 255) / 256, 256, 0, stream>>>(x, XB, S * D / 4);
  build_bqkv<<<(3 * D + 255) / 256, 256, 0, stream>>>(bq, bk, bv, BQKV);
  transpose_f32_bf16<<<dim3(D / 32, HD / 32, H), tb, 0, stream>>>(Wq, WQKVT, HD, D, (long)D * HD, HD);
  transpose_f32_bf16<<<dim3(D / 32, HD / 32, H), tb, 0, stream>>>(Wk, WQKVT + (size_t)D * D, HD, D, (long)D * HD, HD);
  transpose_f32_bf16<<<dim3(D / 32, HD / 32, H), tb, 0, stream>>>(Wv, WQKVT + (size_t)2 * D * D, HD, D, (long)D * HD, HD);
  transpose_f32_bf16<<<dim3(D / 32, D / 32, 1), tb, 0, stream>>>(Wp, WPT, D, D, 0, 0);
  transpose_f32_bf16<<<dim3(D / 32, F / 32, 1), tb, 0, stream>>>(W1, W1T, F, D, 0, 0);
  transpose_f32_bf16<<<dim3(F / 32, D / 32, 1), tb, 0, stream>>>(W2, W2T, D, F, 0, 0);
  // QKV projection (fused, N=6144): BM=128 -> 32x24 = 768 blocks (3 exact CU-waves)
  gemm8p<0, 128><<<dim3((S / 128) * (3 * D / 256)), 512, 0, stream>>>(
      XB, WQKVT, BQKV, nullptr, QKV, nullptr, S, 3 * D, D, 3 * D / 256);
  transpose_bf16<<<dim3(S / 32, D / 32), tb, 0, stream>>>(QKV, VT, 3 * D, S, 2 * D);
  attn_kernel<<<dim3(S / 128, H), 256, 0, stream>>>(QKV, VT, HEADS);
  // output projection + bias + residual -> fp32 pre-LN: 32x8 = 256 blocks (BM=128)
  gemm8p<1, 128><<<dim3((S / 128) * (D / 256)), 512, 0, stream>>>(
      HEADS, WPT, bp, x, nullptr, PRELN, S, D, D, D / 256);
  ln_kernel<<<S, 256, 0, stream>>>(PRELN, gamma, beta, Y);
  // FF1 (+bias, relu) -> bf16: 16x32 = 512 blocks
  gemm8p<2, 256><<<dim3((S / 256) * (F / 256)), 512, 0, stream>>>(
      Y, W1T, b1, nullptr, AB, nullptr, S, F, D, F / 256);
  // FF2 (+bias) -> fp32 out: 32x8 = 256 blocks (BM=128)
  gemm8p<3, 128><<<dim3((S / 128) * (D / 256)), 512, 0, stream>>>(
      AB, W2T, b2, nullptr, nullptr, OUT, S, D, F, D / 256);
}

// Round 8
// 902.971 us; speedup vs baseline: 1.0264x; 1.0264x over previous
//
#include <hip/hip_runtime.h>
#include <hip/hip_bf16.h>
#include <cstdint>
#include <cstddef>

#define S 4096
#define D 2048
#define H 16
#define HD 128
#define F 8192

typedef unsigned short ushort_t;
typedef __attribute__((ext_vector_type(8))) short short8;
typedef __attribute__((ext_vector_type(4))) float floatx4;

__device__ __forceinline__ ushort_t f2bf(float f) {
  union { float f; unsigned u; } v; v.f = f;
  unsigned u = v.u;
  return (ushort_t)((u + 0x7fffu + ((u >> 16) & 1u)) >> 16);
}

__device__ __forceinline__ void async16(void* lds, const void* g) {
  __builtin_amdgcn_global_load_lds(
      (const __attribute__((address_space(1))) unsigned int*)g,
      (__attribute__((address_space(3))) unsigned int*)lds, 16, 0, 0);
}

template <int N>
__device__ __forceinline__ void vmcnt_() {
  static_assert(N >= 0 && N <= 8, "vmcnt range");
  if constexpr (N == 0) asm volatile("s_waitcnt vmcnt(0)" ::: "memory");
  else if constexpr (N == 1) asm volatile("s_waitcnt vmcnt(1)" ::: "memory");
  else if constexpr (N == 2) asm volatile("s_waitcnt vmcnt(2)" ::: "memory");
  else if constexpr (N == 3) asm volatile("s_waitcnt vmcnt(3)" ::: "memory");
  else if constexpr (N == 4) asm volatile("s_waitcnt vmcnt(4)" ::: "memory");
  else if constexpr (N == 5) asm volatile("s_waitcnt vmcnt(5)" ::: "memory");
  else if constexpr (N == 6) asm volatile("s_waitcnt vmcnt(6)" ::: "memory");
  else if constexpr (N == 7) asm volatile("s_waitcnt vmcnt(7)" ::: "memory");
  else asm volatile("s_waitcnt vmcnt(8)" ::: "memory");
}
__device__ __forceinline__ void bar_() { asm volatile("s_barrier" ::: "memory"); }
__device__ __forceinline__ void lgkm0_() {
  asm volatile("s_waitcnt lgkmcnt(0)" ::: "memory");
  __builtin_amdgcn_sched_barrier(0);
}

// ---------------------------------------------------------------- prep kernels

__global__ void cast_bf16(const float* __restrict__ src, ushort_t* __restrict__ dst, int n4) {
  int i = blockIdx.x * blockDim.x + threadIdx.x;
  if (i < n4) {
    float4 v = ((const float4*)src)[i];
    ushort4 o;
    o.x = f2bf(v.x); o.y = f2bf(v.y); o.z = f2bf(v.z); o.w = f2bf(v.w);
    ((ushort4*)dst)[i] = o;
  }
}

__global__ void build_bqkv(const float* __restrict__ bq, const float* __restrict__ bk,
                           const float* __restrict__ bv, float* __restrict__ bqkv) {
  int n = blockIdx.x * blockDim.x + threadIdx.x;
  if (n < 3 * D) {
    float v;
    if (n < D) v = bq[n];
    else if (n < 2 * D) v = bk[n - D];
    else v = bv[n - 2 * D];
    bqkv[n] = v;
  }
}

// dst[c][r] = src[r][c]; fp32 in, bf16 out. block (32,8)
__global__ void transpose_f32_bf16(const float* __restrict__ src, ushort_t* __restrict__ dst,
                                   int ldS, int ldD, long srcBatchStride, long dstBatchRows) {
  __shared__ float t[32][33];
  int b = blockIdx.z;
  src += (size_t)b * srcBatchStride;
  dst += (size_t)b * dstBatchRows * ldD;
  int r0 = blockIdx.x * 32, c0 = blockIdx.y * 32;
  int tx = threadIdx.x, ty = threadIdx.y;
#pragma unroll
  for (int i = 0; i < 4; ++i)
    t[ty + i * 8][tx] = src[(size_t)(r0 + ty + i * 8) * ldS + c0 + tx];
  __syncthreads();
#pragma unroll
  for (int i = 0; i < 4; ++i)
    dst[(size_t)(c0 + ty + i * 8) * ldD + r0 + tx] = f2bf(t[tx][ty + i * 8]);
}

// bf16 transpose with column offset: dst[c][r] = src[r][colOff+c]. block (32,8)
__global__ void transpose_bf16(const ushort_t* __restrict__ src, ushort_t* __restrict__ dst,
                               int ldS, int ldD, int colOff) {
  __shared__ ushort_t t[32][33];
  int r0 = blockIdx.x * 32, c0 = blockIdx.y * 32;
  int tx = threadIdx.x, ty = threadIdx.y;
#pragma unroll
  for (int i = 0; i < 4; ++i)
    t[ty + i * 8][tx] = src[(size_t)(r0 + ty + i * 8) * ldS + colOff + c0 + tx];
  __syncthreads();
#pragma unroll
  for (int i = 0; i < 4; ++i)
    dst[(size_t)(c0 + ty + i * 8) * ldD + r0 + tx] = t[tx][ty + i * 8];
}

// ---------------------------------------------------------------- 4-phase GEMM
// (unchanged from round 4 -- passed; latency/sync-bound per r6 analysis,
// all pipes <35% busy; see round-4 header for the staging ledger)
template <int MODE, int BM>
__global__ __launch_bounds__(512, 2)
void gemm8p(const ushort_t* __restrict__ A, const ushort_t* __restrict__ Bt,
            const float* __restrict__ bias, const float* __restrict__ resid,
            ushort_t* __restrict__ outb, float* __restrict__ outf,
            int M, int N, int K, int gridN) {
  constexpr int MQ = BM / 64;   // m-frags per wave per A-half
  constexpr int LA = BM / 128;  // loads/thread per A half-tile
  __shared__ __align__(16) ushort_t Abuf[2][BM * 64];
  __shared__ __align__(16) ushort_t Bbuf[2][256 * 64];

  const int tid = threadIdx.x;
  const int l = tid & 63, w = tid >> 6;
  const int c16 = l & 15, g = l >> 4;
  const int wm = w >> 2, wn = w & 3;

  // bijective XCD swizzle (m204); consecutive wgid share the A row-panel
  const int nwg = gridDim.x;
  const int q8 = nwg >> 3, r8 = nwg & 7;
  const int xcd = blockIdx.x & 7, bix = blockIdx.x >> 3;
  const int wgid = (xcd < r8 ? xcd * (q8 + 1) : r8 * (q8 + 1) + (xcd - r8) * q8) + bix;
  const int m0 = (wgid / gridN) * BM;
  const int n0 = (wgid % gridN) * 256;

  const size_t Kb = (size_t)K * 2;
  const size_t aHalfB = (size_t)(BM / 2) * Kb;
  const size_t bHalfB = (size_t)128 * Kb;

  const char* aSrc[LA]; char* aLds[LA];
#pragma unroll
  for (int i = 0; i < LA; ++i) {
    int ch = i * 512 + tid;
    int row = ch >> 3;
    aSrc[i] = (const char*)A + (size_t)(m0 + row) * Kb + (((ch ^ row) & 7) << 4);
    aLds[i] = (char*)(&Abuf[0][0]) + ch * 16;
  }
  const char* bSrc[2]; char* bLds[2];
#pragma unroll
  for (int i = 0; i < 2; ++i) {
    int ch = i * 512 + tid;
    int row = ch >> 3;
    bSrc[i] = (const char*)Bt + (size_t)(n0 + row) * Kb + (((ch ^ row) & 7) << 4);
    bLds[i] = (char*)(&Bbuf[0][0]) + ch * 16;
  }

  auto stA = [&](int p, int h, int kByte) {
#pragma unroll
    for (int i = 0; i < LA; ++i)
      async16(aLds[i] + p * (BM * 128) + h * (BM * 64), aSrc[i] + (size_t)h * aHalfB + kByte);
  };
  auto stB = [&](int p, int h, int kByte) {
#pragma unroll
    for (int i = 0; i < 2; ++i)
      async16(bLds[i] + p * 32768 + h * 16384, bSrc[i] + (size_t)h * bHalfB + kByte);
  };

  int rdK[2];
  rdK[0] = ((g ^ (c16 & 7)) << 4);
  rdK[1] = (((4 + g) ^ (c16 & 7)) << 4);
  const char* Ab0 = (const char*)(&Abuf[0][0]);
  const char* Ab1 = Ab0 + BM * 128;
  const char* Bb0 = (const char*)(&Bbuf[0][0]);
  const char* Bb1 = Bb0 + 32768;

  floatx4 acc[2][2][MQ][2];  // [A-half][B-half][mf][nf]
#pragma unroll
  for (int ah = 0; ah < 2; ++ah)
#pragma unroll
    for (int bh = 0; bh < 2; ++bh)
#pragma unroll
      for (int mf = 0; mf < MQ; ++mf)
#pragma unroll
        for (int nf = 0; nf < 2; ++nf) acc[ah][bh][mf][nf] = (floatx4){0.f, 0.f, 0.f, 0.f};

  short8 af[MQ][2], bf0[2][2], bf1[2][2];
  auto ldA = [&](const char* base, int h) {
#pragma unroll
    for (int mf = 0; mf < MQ; ++mf)
#pragma unroll
      for (int kk = 0; kk < 2; ++kk)
        af[mf][kk] = *(const short8*)(base + h * (BM * 64) +
            (wm * (BM / 4) + mf * 16 + c16) * 128 + rdK[kk]);
  };
  auto ldB = [&](const char* base, int h, short8 (&bf)[2][2]) {
#pragma unroll
    for (int nf = 0; nf < 2; ++nf)
#pragma unroll
      for (int kk = 0; kk < 2; ++kk)
        bf[nf][kk] = *(const short8*)(base + h * 16384 +
            (wn * 32 + nf * 16 + c16) * 128 + rdK[kk]);
  };
  auto mma2 = [&](int ah) {
    __builtin_amdgcn_s_setprio(1);
#pragma unroll
    for (int mf = 0; mf < MQ; ++mf)
#pragma unroll
      for (int kk = 0; kk < 2; ++kk) {
#pragma unroll
        for (int nf = 0; nf < 2; ++nf)
          acc[ah][0][mf][nf] = __builtin_amdgcn_mfma_f32_16x16x32_bf16(
              af[mf][kk], bf0[nf][kk], acc[ah][0][mf][nf], 0, 0, 0);
#pragma unroll
        for (int nf = 0; nf < 2; ++nf)
          acc[ah][1][mf][nf] = __builtin_amdgcn_mfma_f32_16x16x32_bf16(
              af[mf][kk], bf1[nf][kk], acc[ah][1][mf][nf], 0, 0, 0);
      }
    __builtin_amdgcn_s_setprio(0);
  };

  // prologue: T0 {A0,B0,B1,A1} + T1 {A0,B0,B1}
  stA(0, 0, 0); stB(0, 0, 0); stB(0, 1, 0); stA(0, 1, 0);
  stA(1, 0, 128); stB(1, 0, 128); stB(1, 1, 128);
  vmcnt_<LA + 4>();
  bar_();

  const int NI = K >> 7;
  for (int i = 0; i < NI; ++i) {
    const bool lastI = (i == NI - 1);
    const int kE = i << 8;

    ldA(Ab0, 0); ldB(Bb0, 0, bf0); ldB(Bb0, 1, bf1);
    stA(1, 1, kE + 128);
    bar_(); lgkm0_();
    mma2(0);
    bar_();

    ldA(Ab0, 1);
    if (!lastI) { stA(0, 0, kE + 256); stB(0, 0, kE + 256); stB(0, 1, kE + 256); }
    bar_(); lgkm0_();
    mma2(1);
    if (lastI) vmcnt_<0>(); else vmcnt_<LA + 4>();
    bar_();

    ldA(Ab1, 0); ldB(Bb1, 0, bf0); ldB(Bb1, 1, bf1);
    if (!lastI) stA(0, 1, kE + 256);
    bar_(); lgkm0_();
    mma2(0);
    bar_();

    ldA(Ab1, 1);
    if (!lastI) { stA(1, 0, kE + 384); stB(1, 0, kE + 384); stB(1, 1, kE + 384); }
    bar_(); lgkm0_();
    mma2(1);
    if (!lastI) { vmcnt_<LA + 4>(); bar_(); }
  }

  // epilogue
#pragma unroll
  for (int ah = 0; ah < 2; ++ah)
#pragma unroll
    for (int bh = 0; bh < 2; ++bh)
#pragma unroll
      for (int nf = 0; nf < 2; ++nf) {
        int gcol = n0 + bh * 128 + wn * 32 + nf * 16 + c16;
        float bj = bias[gcol];
#pragma unroll
        for (int mf = 0; mf < MQ; ++mf) {
          int grow = m0 + ah * (BM / 2) + wm * (BM / 4) + mf * 16 + g * 4;
#pragma unroll
          for (int r = 0; r < 4; ++r) {
            float v = acc[ah][bh][mf][nf][r] + bj;
            size_t o = (size_t)(grow + r) * N + gcol;
            if (MODE == 0) {
              outb[o] = f2bf(v);
            } else if (MODE == 1) {
              outf[o] = v + resid[o];
            } else if (MODE == 2) {
              outb[o] = f2bf(v > 0.f ? v : 0.f);
            } else {
              outf[o] = v;
            }
          }
        }
      }
}

// ---------------------------------------------------------------- flash attention (v5.1)
// = round-7 v5 with the ONE bug fixed: stageV buffer offset was buf*512
// chunks (8192 B) but each V buffer is 1024 chunks (16384 B) -- odd-tile V
// staged into the middle of Vs[0] while reads used &Vs[cur][0]. Now buf*1024,
// matching stageK. Full K+V double-buffer, one counted vmcnt + two barriers
// per tile; Ps is wave-private and u-shared (per-wave DS ordering + lgkm
// waits make the reuse safe); never vmcnt(0) except the last tile.
__global__ __launch_bounds__(256, 2)
void attn_kernel(const ushort_t* __restrict__ QKV, const ushort_t* __restrict__ Vt,
                 ushort_t* __restrict__ heads) {
  const int h = blockIdx.y;
  const int tid = threadIdx.x, w = tid >> 6, l = tid & 63;
  const int g = l >> 4, c = l & 15;
  const int q0 = blockIdx.x * 128 + w * 32;
  const float scale = 0.08838834764831845f;  // 1/sqrt(128)

  __shared__ __align__(16) ushort_t Ks[2][64 * 128];  // [buf][t][d] rows 256B, chunk-swizzled
  __shared__ __align__(16) ushort_t Vs[2][128 * 64];  // [buf][e][t] rows 128B, chunk-swizzled
  __shared__ __align__(16) ushort_t Ps[4][16][72];    // wave-private, u-shared, pad-72

  short8 qf[2][4];
#pragma unroll
  for (int u = 0; u < 2; ++u)
#pragma unroll
    for (int k0 = 0; k0 < 4; ++k0)
      qf[u][k0] = *(const short8*)(QKV + (size_t)(q0 + u * 16 + c) * (3 * D) + h * HD + k0 * 32 + g * 8);

  floatx4 o[2][8];
#pragma unroll
  for (int u = 0; u < 2; ++u)
#pragma unroll
    for (int j = 0; j < 8; ++j) o[u][j] = (floatx4){0.f, 0.f, 0.f, 0.f};
  float l_run[2] = {0.f, 0.f};

  auto stageK = [&](int buf, int t0) {
#pragma unroll
    for (int cc = 0; cc < 4; ++cc) {
      int slot = cc * 256 + tid;
      int krow = slot >> 4, kch = slot & 15;
      const char* gk = (const char*)QKV +
          ((size_t)(t0 + krow) * (3 * D) + D + h * HD) * 2 + ((kch ^ (krow & 15)) << 4);
      async16((char*)(&Ks[0][0]) + (size_t)(buf * 1024 + cc * 256 + w * 64) * 16, gk);
    }
  };
  auto stageV = [&](int buf, int t0) {
#pragma unroll
    for (int cc = 0; cc < 4; ++cc) {
      int slot = cc * 256 + tid;
      int vrow = slot >> 3, vch = slot & 7;
      const char* gv = (const char*)Vt +
          ((size_t)(h * HD + vrow) * S + t0) * 2 + ((vch ^ (vrow & 7)) << 4);
      async16((char*)(&Vs[0][0]) + (size_t)(buf * 1024 + cc * 256 + w * 64) * 16, gv);
    }
  };

  // prologue: stage tile 0
  stageK(0, 0);
  stageV(0, 0);

  for (int t0 = 0, ti = 0; t0 < S; t0 += 64, ++ti) {
    const int cur = ti & 1, nxt = cur ^ 1;
    const bool lastT = (t0 + 64 >= S);

    if (!lastT) { stageK(nxt, t0 + 64); stageV(nxt, t0 + 64); }
    if (lastT) vmcnt_<0>(); else vmcnt_<8>();  // tile t resident
    bar_();

    const ushort_t* Kb = &Ks[cur][0];
    const ushort_t* Vb = &Vs[cur][0];

    // V fragments to registers (shared across both u halves)
    short8 vf[8][2];
#pragma unroll
    for (int j = 0; j < 8; ++j)
#pragma unroll
      for (int tk = 0; tk < 2; ++tk)
        vf[j][tk] = *(const short8*)(Vb + (j * 16 + c) * 64 + (((tk * 4 + g) ^ (c & 7)) << 3));

    // QK^T
    floatx4 sc[2][4];
#pragma unroll
    for (int u = 0; u < 2; ++u)
#pragma unroll
      for (int tt = 0; tt < 4; ++tt) sc[u][tt] = (floatx4){0.f, 0.f, 0.f, 0.f};
#pragma unroll
    for (int tt = 0; tt < 4; ++tt) {
      short8 kf[4];
#pragma unroll
      for (int k0 = 0; k0 < 4; ++k0)
        kf[k0] = *(const short8*)(Kb + (tt * 16 + c) * 128 + (((k0 * 4 + g) ^ c) << 3));
#pragma unroll
      for (int u = 0; u < 2; ++u)
#pragma unroll
        for (int k0 = 0; k0 < 4; ++k0)
          sc[u][tt] = __builtin_amdgcn_mfma_f32_16x16x32_bf16(kf[k0], qf[u][k0], sc[u][tt], 0, 0, 0);
    }

    // softmax(u) -> Ps -> P-fragments
    auto smax = [&](int u) {
#pragma unroll
      for (int tt = 0; tt < 4; ++tt) {
        float p0 = __expf(sc[u][tt][0] * scale);
        float p1 = __expf(sc[u][tt][1] * scale);
        float p2 = __expf(sc[u][tt][2] * scale);
        float p3 = __expf(sc[u][tt][3] * scale);
        l_run[u] += p0 + p1 + p2 + p3;
        unsigned r0, r1;
        asm("v_cvt_pk_bf16_f32 %0, %1, %2" : "=v"(r0) : "v"(p0), "v"(p1));
        asm("v_cvt_pk_bf16_f32 %0, %1, %2" : "=v"(r1) : "v"(p2), "v"(p3));
        uint2 pk; pk.x = r0; pk.y = r1;
        *reinterpret_cast<uint2*>(&Ps[w][c][tt * 16 + g * 4]) = pk;
      }
    };
    auto pv = [&](int u, short8 (&pf)[2]) {
#pragma unroll
      for (int j = 0; j < 8; ++j)
#pragma unroll
        for (int tk = 0; tk < 2; ++tk)
          o[u][j] = __builtin_amdgcn_mfma_f32_16x16x32_bf16(pf[tk], vf[j][tk], o[u][j], 0, 0, 0);
    };

    short8 pf0[2], pf1[2];
    smax(0);
    lgkm0_();  // u0 writes visible
#pragma unroll
    for (int tk = 0; tk < 2; ++tk)
      pf0[tk] = *reinterpret_cast<const short8*>(&Ps[w][c][tk * 32 + g * 8]);
    lgkm0_();  // u0 reads retired -> safe to overwrite Ps
    smax(1);   // overlaps PV(u0) in scheduler
    pv(0, pf0);
    lgkm0_();  // u1 writes visible
#pragma unroll
    for (int tk = 0; tk < 2; ++tk)
      pf1[tk] = *reinterpret_cast<const short8*>(&Ps[w][c][tk * 32 + g * 8]);
    lgkm0_();
    pv(1, pf1);

    bar_();  // protect buf[cur] + Ps before next iter's stage/smax
  }

#pragma unroll
  for (int u = 0; u < 2; ++u) {
    float lt = l_run[u];
    lt += __shfl_xor(lt, 16);
    lt += __shfl_xor(lt, 32);
    float linv[4];
#pragma unroll
    for (int r = 0; r < 4; ++r) linv[r] = 1.f / __shfl(lt, g * 4 + r);
    ushort_t* hp = heads + (size_t)(q0 + u * 16 + g * 4) * D + h * HD + c;
#pragma unroll
    for (int j = 0; j < 8; ++j)
#pragma unroll
      for (int r = 0; r < 4; ++r)
        hp[(size_t)r * D + j * 16] = f2bf(o[u][j][r] * linv[r]);
  }
}

// ---------------------------------------------------------------- LayerNorm
__global__ __launch_bounds__(256)
void ln_kernel(const float* __restrict__ preln, const float* __restrict__ gamma,
               const float* __restrict__ beta, ushort_t* __restrict__ y) {
  int row = blockIdx.x, tid = threadIdx.x;
  const float* p = preln + (size_t)row * D;
  float vals[8];
  float sum = 0.f, ss = 0.f;
#pragma unroll
  for (int k = 0; k < 8; ++k) {
    float v = p[tid + k * 256];
    vals[k] = v; sum += v; ss += v * v;
  }
#pragma unroll
  for (int off = 32; off >= 1; off >>= 1) {
    sum += __shfl_xor(sum, off);
    ss += __shfl_xor(ss, off);
  }
  __shared__ float s1[4], s2[4];
  int w = tid >> 6, l = tid & 63;
  if (l == 0) { s1[w] = sum; s2[w] = ss; }
  __syncthreads();
  sum = s1[0] + s1[1] + s1[2] + s1[3];
  ss = s2[0] + s2[1] + s2[2] + s2[3];
  float mu = sum / (float)D;
  float var = ss / (float)D - mu * mu;
  float rs = rsqrtf(var + 1e-5f);
  ushort_t* yr = y + (size_t)row * D;
#pragma unroll
  for (int k = 0; k < 8; ++k) {
    int d = tid + k * 256;
    yr[d] = f2bf((vals[k] - mu) * rs * gamma[d] + beta[d]);
  }
}

// ---------------------------------------------------------------- launch

extern "C" void kernel_launch(void* const* d_in, const int* in_sizes, int n_in,
                              void* d_out, int out_size, void* d_ws, size_t ws_size,
                              hipStream_t stream) {
  const float* x = (const float*)d_in[0];
  const float* Wq = (const float*)d_in[1];
  const float* bq = (const float*)d_in[2];
  const float* Wk = (const float*)d_in[3];
  const float* bk = (const float*)d_in[4];
  const float* Wv = (const float*)d_in[5];
  const float* bv = (const float*)d_in[6];
  const float* Wp = (const float*)d_in[7];
  const float* bp = (const float*)d_in[8];
  const float* W1 = (const float*)d_in[9];
  const float* b1 = (const float*)d_in[10];
  const float* W2 = (const float*)d_in[11];
  const float* b2 = (const float*)d_in[12];
  const float* gamma = (const float*)d_in[13];
  const float* beta = (const float*)d_in[14];

  char* ws = (char*)d_ws;
  ushort_t* WQKVT = (ushort_t*)(ws + 0);          // 25,165,824  [dead after QKV gemm]
  ushort_t* XB    = (ushort_t*)(ws + 25165824);   // 16,777,216  [dead after QKV gemm]
  float*    BQKV  = (float*)(ws + 41943040);      //     24,576
  ushort_t* WPT   = (ushort_t*)(ws + 41975808);   //  8,388,608
  ushort_t* W1T   = (ushort_t*)(ws + 50364416);   // 33,554,432
  ushort_t* W2T   = (ushort_t*)(ws + 83918848);   // 33,554,432
  ushort_t* QKV   = (ushort_t*)(ws + 117473280);  // 50,331,648  [dead after attn]
  ushort_t* HEADS = (ushort_t*)(ws + 167804928);  // 16,777,216  [dead after proj]
  ushort_t* VT    = (ushort_t*)(ws + 184582144);  // 16,777,216  [dead after attn]
  float*    PRELN = (float*)(ws + 0);             // 33,554,432 over WQKVT+XB
  ushort_t* AB    = (ushort_t*)(ws + 117473280);  // 67,108,864 over QKV+HEADS
  ushort_t* Y     = (ushort_t*)(ws + 184582144);  // 16,777,216 over VT
  float* OUT = (float*)d_out;

  dim3 tb(32, 8);
  cast_bf16<<<(S * D / 4 + 255) / 256, 256, 0, stream>>>(x, XB, S * D / 4);
  build_bqkv<<<(3 * D + 255) / 256, 256, 0, stream>>>(bq, bk, bv, BQKV);
  transpose_f32_bf16<<<dim3(D / 32, HD / 32, H), tb, 0, stream>>>(Wq, WQKVT, HD, D, (long)D * HD, HD);
  transpose_f32_bf16<<<dim3(D / 32, HD / 32, H), tb, 0, stream>>>(Wk, WQKVT + (size_t)D * D, HD, D, (long)D * HD, HD);
  transpose_f32_bf16<<<dim3(D / 32, HD / 32, H), tb, 0, stream>>>(Wv, WQKVT + (size_t)2 * D * D, HD, D, (long)D * HD, HD);
  transpose_f32_bf16<<<dim3(D / 32, D / 32, 1), tb, 0, stream>>>(Wp, WPT, D, D, 0, 0);
  transpose_f32_bf16<<<dim3(D / 32, F / 32, 1), tb, 0, stream>>>(W1, W1T, F, D, 0, 0);
  transpose_f32_bf16<<<dim3(F / 32, D / 32, 1), tb, 0, stream>>>(W2, W2T, D, F, 0, 0);
  // QKV projection (fused, N=6144): BM=256 -> 16x24 = 384 blocks
  gemm8p<0, 256><<<dim3((S / 256) * (3 * D / 256)), 512, 0, stream>>>(
      XB, WQKVT, BQKV, nullptr, QKV, nullptr, S, 3 * D, D, 3 * D / 256);
  transpose_bf16<<<dim3(S / 32, D / 32), tb, 0, stream>>>(QKV, VT, 3 * D, S, 2 * D);
  attn_kernel<<<dim3(S / 128, H), 256, 0, stream>>>(QKV, VT, HEADS);
  // output projection + bias + residual -> fp32 pre-LN: 32x8 = 256 blocks (BM=128)
  gemm8p<1, 128><<<dim3((S / 128) * (D / 256)), 512, 0, stream>>>(
      HEADS, WPT, bp, x, nullptr, PRELN, S, D, D, D / 256);
  ln_kernel<<<S, 256, 0, stream>>>(PRELN, gamma, beta, Y);
  // FF1 (+bias, relu) -> bf16: 16x32 = 512 blocks
  gemm8p<2, 256><<<dim3((S / 256) * (F / 256)), 512, 0, stream>>>(
      Y, W1T, b1, nullptr, AB, nullptr, S, F, D, F / 256);
  // FF2 (+bias) -> fp32 out: 32x8 = 256 blocks (BM=128)
  gemm8p<3, 128><<<dim3((S / 128) * (D / 256)), 512, 0, stream>>>(
      AB, W2T, b2, nullptr, nullptr, OUT, S, D, F, D / 256);
}